// Round 1
// baseline (413.934 us; speedup 1.0000x reference)
//
#include <hip/hip_runtime.h>

// Bilateral-grid slicing:
//   grid : (B=16, C=12, D=8, H=16, W=16) f32
//   guide: (B=16, 1, GH=512, GW=512) f32
//   out  : (B=16, C=12, GH=512, GW=512) f32
//
// Memory-bound: out ~201MB write dominates. grid (1.5MB) is L2-resident;
// weights/offsets computed once per pixel, reused across 12 channels.

__global__ __launch_bounds__(256) void slice_kernel(
    const float* __restrict__ grid,
    const float* __restrict__ guide,
    float* __restrict__ out)
{
    constexpr int C = 12, D = 8, H = 16, W = 16, GH = 512, GW = 512;
    constexpr int DHW = D * H * W;   // 2048
    constexpr int HW  = H * W;       // 256
    constexpr int NQ  = 16 * GH * GW / 4;  // quads of pixels: 1048576

    const int stride = gridDim.x * blockDim.x;
    for (int q = blockIdx.x * blockDim.x + threadIdx.x; q < NQ; q += stride) {
        const int pix  = q << 2;            // linear pixel index (b*GH + h)*GW + w
        const int w0   = pix & (GW - 1);
        const int rest = pix >> 9;          // / GW
        const int h    = rest & (GH - 1);
        const int b    = rest >> 9;         // / GH

        // guide is laid out exactly in pixel-linear order; 16B-aligned (w0 % 4 == 0)
        const float4 g4 = *reinterpret_cast<const float4*>(guide + pix);
        const float gz[4] = {g4.x, g4.y, g4.z, g4.w};

        // y coordinate (shared by the 4 pixels)
        float yy  = ((float)h - 256.0f) * (1.0f / 256.0f);
        float iy  = ((yy + 1.0f) * (float)H - 1.0f) * 0.5f;
        iy        = fminf(fmaxf(iy, 0.0f), (float)(H - 1));
        float iy0f = floorf(iy);
        float fy   = iy - iy0f;
        int   iy0  = (int)iy0f;
        int   dy   = (iy0 < H - 1) ? W : 0;

        int   off[4][8];
        float wt[4][8];
#pragma unroll
        for (int j = 0; j < 4; ++j) {
            int   w   = w0 + j;
            float xx  = ((float)w - 256.0f) * (1.0f / 256.0f);
            float ix  = ((xx + 1.0f) * (float)W - 1.0f) * 0.5f;
            ix        = fminf(fmaxf(ix, 0.0f), (float)(W - 1));
            float ix0f = floorf(ix);
            float fx   = ix - ix0f;
            int   ix0  = (int)ix0f;
            int   dx   = (ix0 < W - 1) ? 1 : 0;

            float z   = gz[j];
            float iz  = ((z + 1.0f) * (float)D - 1.0f) * 0.5f;
            iz        = fminf(fmaxf(iz, 0.0f), (float)(D - 1));
            float iz0f = floorf(iz);
            float fz   = iz - iz0f;
            int   iz0  = (int)iz0f;
            int   dz   = (iz0 < D - 1) ? HW : 0;

            int base = (iz0 * H + iy0) * W + ix0;

            float wx1 = fx, wx0 = 1.0f - fx;
            float wy1 = fy, wy0 = 1.0f - fy;
            float wz1 = fz, wz0 = 1.0f - fz;
            // (wz*wy)*wx matches the reference's left-to-right product order
            float wzy[4] = {wz0 * wy0, wz0 * wy1, wz1 * wy0, wz1 * wy1};
#pragma unroll
            for (int k = 0; k < 8; ++k) {
                off[j][k] = base + ((k & 1) ? dx : 0) + ((k & 2) ? dy : 0) + ((k & 4) ? dz : 0);
                wt[j][k]  = wzy[k >> 1] * ((k & 1) ? wx1 : wx0);
            }
        }

        const float* gb = grid + (size_t)b * C * DHW;
        for (int c = 0; c < C; ++c) {
            const float* gc = gb + c * DHW;
            float acc[4];
#pragma unroll
            for (int j = 0; j < 4; ++j) {
                float a = 0.0f;
#pragma unroll
                for (int k = 0; k < 8; ++k)
                    a = fmaf(wt[j][k], gc[off[j][k]], a);
                acc[j] = a;
            }
            size_t o = (((size_t)(b * C + c) * GH + h) * GW + w0);
            *reinterpret_cast<float4*>(out + o) = make_float4(acc[0], acc[1], acc[2], acc[3]);
        }
    }
}

extern "C" void kernel_launch(void* const* d_in, const int* in_sizes, int n_in,
                              void* d_out, int out_size, void* d_ws, size_t ws_size,
                              hipStream_t stream) {
    const float* grid  = (const float*)d_in[0];
    const float* guide = (const float*)d_in[1];
    float* out = (float*)d_out;
    (void)in_sizes; (void)n_in; (void)out_size; (void)d_ws; (void)ws_size;

    dim3 block(256);
    dim3 gridDim(2048);   // grid-stride: 1048576 quads / (2048*256) = 2 iters/thread
    hipLaunchKernelGGL(slice_kernel, gridDim, block, 0, stream, grid, guide, out);
}

// Round 2
// 42.965 us; speedup vs baseline: 9.6343x; 9.6343x over previous
//
#include <hip/hip_runtime.h>

// Bilateral-grid slicing, LDS-staged.
//   grid : (B=16, C=12, D=8, H=16, W=16) f32
//   guide: (B=16, 1, 512, 512) f32
//   out  : (B=16, C=12, 512, 512) f32
//
// Block = 256 threads, covers 4 rows (2048 px) of one batch.
// Stages the needed 4 y-slices of the grid into LDS with layout
//   S[((c*4 + yloc)*16 + x)*9 + z]   (z innermost, x-stride 9 for bank spread)
// so each trilinear corner-pair (z0,z0+1) is one ds_read2_b32 and the z-lerp
// happens in registers. 8 gathers/px/ch -> 4 LDS read2 + 4 fma.

constexpr int C = 12, D = 8, H = 16, W = 16, GH = 512, GW = 512;
constexpr int XST = 9;               // x stride in LDS floats (8 z + 1 pad)
constexpr int YS = 4;                // staged y-slices
constexpr int YST = 16 * XST;        // 144
constexpr int CST = YS * YST;        // 576
constexpr int LDS_FLOATS = C * CST;  // 6912 (27 KB)

__global__ __launch_bounds__(256) void slice_kernel(
    const float* __restrict__ grid,
    const float* __restrict__ guide,
    float* __restrict__ out)
{
    __shared__ float S[LDS_FLOATS];
    const int t   = threadIdx.x;
    const int bid = blockIdx.x;
    const int b   = bid >> 7;            // 128 blocks per batch
    const int h0  = (bid & 127) << 2;    // 4 rows per block

    // y-slices needed by rows h0..h0+3: iy = h/32 - 0.5 -> iy0 in {F, F+1}
    const int F      = (int)floorf((float)h0 * 0.03125f - 0.5f);
    const int y_base = min(max(F, 0), H - YS);   // [0, 12]

    // ---- hoist guide loads (independent of LDS) ----
    float4 g4q[2];
    int    pixq[2], hq[2], w0q[2];
#pragma unroll
    for (int qq = 0; qq < 2; ++qq) {
        int q   = t + (qq << 8);         // local quad 0..511
        int px  = q << 2;                // local pixel 0..2047
        int row = px >> 9;
        w0q[qq] = px & (GW - 1);
        hq[qq]  = h0 + row;
        pixq[qq] = ((b << 9) + hq[qq]) * GW + w0q[qq];
        g4q[qq] = *reinterpret_cast<const float4*>(guide + pixq[qq]);
    }

    // ---- stage grid -> LDS ----
    const float* gb = grid + (size_t)b * (C * D * H * W);
#pragma unroll
    for (int iter = 0; iter < 6; ++iter) {
        int i    = t + (iter << 8);      // 0..1535 float4-chunks
        int x4   = i & 3;
        int yloc = (i >> 2) & 3;
        int z    = (i >> 4) & 7;
        int c    = i >> 7;
        const float4 v = *reinterpret_cast<const float4*>(
            gb + ((c * D + z) * H + (y_base + yloc)) * W + (x4 << 2));
        int x0 = x4 << 2;
        int db = (c * YS + yloc) * YST + z;
        S[db + (x0 + 0) * XST] = v.x;
        S[db + (x0 + 1) * XST] = v.y;
        S[db + (x0 + 2) * XST] = v.z;
        S[db + (x0 + 3) * XST] = v.w;
    }
    __syncthreads();

#pragma unroll
    for (int qq = 0; qq < 2; ++qq) {
        const int h  = hq[qq];
        const int w0 = w0q[qq];
        const float4 g4 = g4q[qq];
        const float gz[4] = {g4.x, g4.y, g4.z, g4.w};

        // y interpolation (shared by the 4 pixels: same h)
        float iy = (float)h * 0.03125f - 0.5f;
        iy = fminf(fmaxf(iy, 0.0f), 15.0f);
        float iy0f = floorf(iy);
        float fy   = iy - iy0f;
        int   iy0  = (int)iy0f;
        const int dy = (iy0 < H - 1) ? YST : 0;
        const int yoff = (iy0 - y_base) * YST;

        int   pb[4], dxv[4];
        float fz[4], w00[4], w01[4], w10[4], w11[4];
#pragma unroll
        for (int j = 0; j < 4; ++j) {
            int w = w0 + j;
            float ix = (float)w * 0.03125f - 0.5f;
            ix = fminf(fmaxf(ix, 0.0f), 15.0f);
            float ix0f = floorf(ix);
            float fx   = ix - ix0f;
            int   ix0  = (int)ix0f;
            dxv[j] = (ix0 < W - 1) ? XST : 0;

            float iz = ((gz[j] + 1.0f) * 8.0f - 1.0f) * 0.5f;
            iz = fminf(fmaxf(iz, 0.0f), 7.0f);
            float iz0f = floorf(iz);
            float f    = iz - iz0f;
            int   iz0  = (int)iz0f;
            int   iz0c = min(iz0, D - 2);        // clamp so pair (z,z+1) in range
            f += (float)(iz0 - iz0c);            // iz0==7 -> f=1 -> picks v[7] exactly
            fz[j] = f;
            pb[j] = yoff + ix0 * XST + iz0c;

            w00[j] = (1.0f - fy) * (1.0f - fx);
            w01[j] = (1.0f - fy) * fx;
            w10[j] = fy * (1.0f - fx);
            w11[j] = fy * fx;
        }

        const size_t obase = (((size_t)b * C) * GH + h) * GW + w0;
#pragma unroll
        for (int c = 0; c < C; ++c) {
            float acc[4];
#pragma unroll
            for (int j = 0; j < 4; ++j) {
                const int base = c * CST + pb[j];
                const int dx   = dxv[j];
                float a0 = S[base],           a1 = S[base + 1];
                float b0 = S[base + dx],      b1 = S[base + dx + 1];
                float c0 = S[base + dy],      c1 = S[base + dy + 1];
                float d0 = S[base + dy + dx], d1 = S[base + dy + dx + 1];
                float f  = fz[j];
                float va = a0 + f * (a1 - a0);
                float vb = b0 + f * (b1 - b0);
                float vc = c0 + f * (c1 - c0);
                float vd = d0 + f * (d1 - d0);
                acc[j] = ((w00[j] * va + w01[j] * vb) + w10[j] * vc) + w11[j] * vd;
            }
            *reinterpret_cast<float4*>(out + obase + (size_t)c * GH * GW) =
                make_float4(acc[0], acc[1], acc[2], acc[3]);
        }
    }
}

extern "C" void kernel_launch(void* const* d_in, const int* in_sizes, int n_in,
                              void* d_out, int out_size, void* d_ws, size_t ws_size,
                              hipStream_t stream) {
    const float* grid  = (const float*)d_in[0];
    const float* guide = (const float*)d_in[1];
    float* out = (float*)d_out;
    (void)in_sizes; (void)n_in; (void)out_size; (void)d_ws; (void)ws_size;

    dim3 block(256);
    dim3 gridDim(2048);   // 16 batches * 128 row-groups
    hipLaunchKernelGGL(slice_kernel, gridDim, block, 0, stream, grid, guide, out);
}